// Round 11
// baseline (115.868 us; speedup 1.0000x reference)
//
#include <hip/hip_runtime.h>
#include <stdint.h>

#define B_SZ 2048
#define F_SZ 24
#define E_SZ 128
#define P_SZ 276            // F*(F-1)/2
#define BT   256            // batch rows per block (8 waves x 32 cols)
#define SEGLEN 4
#define NSEG 78             // sum over fq=1..23 of ceil(fq/4)
#define NWG  (NSEG * 8)     // 624

#define XT_ELEMS (B_SZ * F_SZ * E_SZ)   // 6,291,456 (12.6 MB bf16)
#define KB_ELEMS (P_SZ * E_SZ * E_SZ)   // 4,521,984 ( 9.0 MB bf16)
#define WS_NEED  ((size_t)(XT_ELEMS + KB_ELEMS) * 2)   // 21.6 MB

#define XPREP_BLKS (F_SZ * 64)          // 1536  (one per (f, 32-row group))
#define KPREP_BLKS (KB_ELEMS / 2048)    // 2208

typedef __bf16 bf16x8 __attribute__((ext_vector_type(8)));
typedef __bf16 bf16x4 __attribute__((ext_vector_type(4)));
typedef float  f32x16 __attribute__((ext_vector_type(16)));

// ---- prepack ----------------------------------------------------------------
// xft[f][grp<64][slot<512][8]: slot s holds
//   x[grp*32 + (s&31)][f][(s>>6)*16 + ((s>>5)&1)*8 + i]   (bf16)
// Serves BOTH MFMA B-fragments (slot = kk*64 + lane) AND epilogue Xq reads
// (slot = (2mt+(q>>1))*64 + (q&1)*32 + l31, elem hi*4+i), both coalesced.
// Built via LDS transpose so global reads AND writes are coalesced.
// kb[p][d][slot]: pre-XOR-swizzled K so a linear LDS DMA lands swizzled.
__global__ __launch_bounds__(256) void prepack_all(
    const float* __restrict__ x, const float* __restrict__ kern,
    __bf16* __restrict__ xft, __bf16* __restrict__ kb)
{
    const int bid = blockIdx.x;
    const int tid = threadIdx.x;
    if (bid < XPREP_BLKS) {
        const int f = bid >> 6, grp = bid & 63;
        __shared__ float sT[32][129];       // +1 pad: conflict-free col reads
        {
            const int row = tid >> 3, c0 = (tid & 7) * 16;
            const float* src = x + ((size_t)(grp * 32 + row) * F_SZ + f) * E_SZ + c0;
            float4 v0 = ((const float4*)src)[0];
            float4 v1 = ((const float4*)src)[1];
            float4 v2 = ((const float4*)src)[2];
            float4 v3 = ((const float4*)src)[3];
            *(float4*)&sT[row][c0]      = v0;
            *(float4*)&sT[row][c0 + 4]  = v1;
            *(float4*)&sT[row][c0 + 8]  = v2;
            *(float4*)&sT[row][c0 + 12] = v3;
        }
        __syncthreads();
        __bf16* dst = xft + (size_t)(f * 64 + grp) * 4096;
#pragma unroll
        for (int u = 0; u < 2; ++u) {
            const int s = tid * 2 + u;              // slot 0..511
            const int row = s & 31;
            const int e0  = (s >> 6) * 16 + ((s >> 5) & 1) * 8;
            bf16x8 h;
#pragma unroll
            for (int i = 0; i < 8; ++i)
                h[i] = (__bf16)sT[row][e0 + i];
            *(bf16x8*)(dst + s * 8) = h;
        }
    } else {
        int g = (bid - XPREP_BLKS) * 256 + tid;     // 16B-slot id
        int p = g >> 11, r = g & 2047;
        int d = r >> 4, s = r & 15;
        const float* src = kern + ((size_t)d * P_SZ + p) * E_SZ + ((s ^ (d & 15)) << 3);
        float4 v0 = *(const float4*)src;
        float4 v1 = *(const float4*)(src + 4);
        bf16x8 h;
        h[0] = (__bf16)v0.x; h[1] = (__bf16)v0.y; h[2] = (__bf16)v0.z; h[3] = (__bf16)v0.w;
        h[4] = (__bf16)v1.x; h[5] = (__bf16)v1.y; h[6] = (__bf16)v1.z; h[7] = (__bf16)v1.w;
        *(bf16x8*)(kb + (size_t)g * 8) = h;
    }
}

// Per-pair MFMA + lane-local epilogue. D layout (32x32x16):
// col = lane&31 (= b), row(d) = (reg&3) + 8*(reg>>2) + 4*hi (+32*mt)
#define COMPUTE_PAIR(KBUF, XP, PJ)                                            \
  {                                                                           \
    float s0_ = 0.f, s1_ = 0.f;                                               \
    _Pragma("unroll")                                                         \
    for (int mt = 0; mt < 4; ++mt) {                                          \
      f32x16 acc;                                                             \
      _Pragma("unroll")                                                       \
      for (int q = 0; q < 16; ++q) acc[q] = 0.f;                              \
      const int arow_ = mt * 32 + l31;                                        \
      const short* kRow_ = &(KBUF)[arow_ * E_SZ];                             \
      const int asw_ = (arow_ & 15) << 3;                                     \
      _Pragma("unroll")                                                       \
      for (int kk = 0; kk < 8; ++kk) {                                        \
        bf16x8 afr_ = *(const bf16x8*)&kRow_[((kk * 2 + hi) << 3) ^ asw_];    \
        acc = __builtin_amdgcn_mfma_f32_32x32x16_bf16(afr_, (XP)[kk], acc,    \
                                                      0, 0, 0);               \
      }                                                                       \
      _Pragma("unroll")                                                       \
      for (int q = 0; q < 4; ++q) {                                           \
        const bf16x4 xq_ = xqr[mt][q];                                        \
        s0_ += acc[q*4+0]*(float)xq_[0] + acc[q*4+1]*(float)xq_[1];           \
        s1_ += acc[q*4+2]*(float)xq_[2] + acc[q*4+3]*(float)xq_[3];           \
      }                                                                       \
    }                                                                         \
    float sv_ = s0_ + s1_;                                                    \
    sv_ += __shfl_xor(sv_, 32);                                               \
    if (hi == 0) out[(size_t)(grp * 32 + l31) * P_SZ + (PJ)] = sv_;           \
  }

// ---- main: block = (fq-segment of <=4 pairs, 256-row batch tile).
//      Xq in regs for the whole chain; per pair: K (32KB DMA, LDS dbuf) +
//      Xp (8 reg loads), both issued ONE PAIR AHEAD with counted vmcnt(12).
__global__ __launch_bounds__(512, 4) void opn_main(
    const __bf16* __restrict__ xft, const __bf16* __restrict__ kb,
    float* __restrict__ out)
{
    __shared__ short sK0[E_SZ * E_SZ];  // 32 KB each, double buffer
    __shared__ short sK1[E_SZ * E_SZ];

    const int tid = threadIdx.x, w = tid >> 6, lane = tid & 63;
    const int l31 = lane & 31, hi = lane >> 5;
    const int orig = blockIdx.x;
    const int bb = orig & 7;            // batch tile (round-robin XCDs)
    const int il = orig >> 3;           // 0..77, long segments first

    // il -> (fq, q0, len), fq DESCENDING so long chains dispatch first
    int s = il, fq = 23;
    for (;;) { int ns = (fq + 3) >> 2; if (s < ns) break; s -= ns; --fq; }
    const int q0  = s * SEGLEN;
    const int len = (fq - q0 < SEGLEN) ? (fq - q0) : SEGLEN;

    const int grp = bb * 8 + w;         // this wave's 32-row batch group

    // p of pair (fp, fq), triu row-major, F=24
    auto pOf = [&](int fp) { return fp * 23 - (fp * (fp - 1)) / 2 + (fq - fp - 1); };

    auto stage_k = [&](short* dst, int p) {   // linear copy of pre-swz K_p
        const __bf16* kp = kb + (size_t)p * (E_SZ * E_SZ);
#pragma unroll
        for (int t = 0; t < 4; ++t) {
            const int base = (w * 4 + t) * 64;
            __builtin_amdgcn_global_load_lds(
                (const __attribute__((address_space(1))) void*)(kp + (size_t)(base + lane) * 8),
                (__attribute__((address_space(3))) void*)(&dst[base * 8]),
                16, 0, 0);
        }
    };
    auto load_xp = [&](bf16x8* xp, int fp) {  // 8 coalesced dwordx4
        const __bf16* xpb = xft + (size_t)(fp * 64 + grp) * 4096 + lane * 8;
#pragma unroll
        for (int kk = 0; kk < 8; ++kk)
            xp[kk] = *(const bf16x8*)(xpb + kk * 512);
    };

    // Xq for feature fq: 16 coalesced 8B loads, held all chain long.
    bf16x4 xqr[4][4];
    {
        const __bf16* xqb = xft + (size_t)(fq * 64 + grp) * 4096 + l31 * 8 + hi * 4;
#pragma unroll
        for (int mt = 0; mt < 4; ++mt)
#pragma unroll
            for (int q = 0; q < 4; ++q)
                xqr[mt][q] = *(const bf16x4*)(xqb + (mt * 2 + (q >> 1)) * 512 + (q & 1) * 256);
    }

    bf16x8 xpA[8], xpB[8];
    stage_k(sK0, pOf(q0));              // pair 0: K + Xp in flight (12 ops)
    load_xp(xpA, q0);

#pragma unroll
    for (int j = 0; j < SEGLEN; ++j) {
        if (j >= len) break;
        if (j + 1 < len) {              // issue pair j+1 into the other buffer
            if ((j + 1) & 1) { stage_k(sK1, pOf(q0 + j + 1)); load_xp(xpB, q0 + j + 1); }
            else             { stage_k(sK0, pOf(q0 + j + 1)); load_xp(xpA, q0 + j + 1); }
            asm volatile("s_waitcnt vmcnt(12)" ::: "memory");  // pair j done
        } else {
            asm volatile("s_waitcnt vmcnt(0)" ::: "memory");
        }
        __builtin_amdgcn_sched_barrier(0);
        __builtin_amdgcn_s_barrier();   // all waves' K_j staged
        if (j & 1) COMPUTE_PAIR(sK1, xpB, pOf(q0 + j))
        else       COMPUTE_PAIR(sK0, xpA, pOf(q0 + j))
        __builtin_amdgcn_s_barrier();   // buffer free before j+2's DMA
    }
}

// ---------------- fallback (round-2 kernel, used if ws too small) -----------
__global__ __launch_bounds__(512, 4) void opn_fallback(
    const float* __restrict__ x, const float* __restrict__ kern,
    float* __restrict__ out)
{
    __shared__ short sA[128 * E_SZ];
    __shared__ short sB[E_SZ * E_SZ];
    __shared__ float red[2][128];

    const int tid = threadIdx.x;
    const int orig = blockIdx.x;
    const int nwg2 = P_SZ * 16;
    const int wgid = (orig & 7) * (nwg2 / 8) + (orig >> 3);
    const int p  = wgid >> 4;
    const int bb = wgid & 15;
    const int b0 = bb * 128;

    int fp = 0, rem = p;
    while (rem >= F_SZ - 1 - fp) { rem -= F_SZ - 1 - fp; ++fp; }
    const int fq = fp + 1 + rem;

#pragma unroll
    for (int k = 0; k < 4; ++k) {
        int i = tid + k * 512;
        int r = i >> 4, s8 = i & 15;
        const float* src = x + ((size_t)(b0 + r) * F_SZ + fp) * E_SZ + s8 * 8;
        float4 v0 = *(const float4*)src;
        float4 v1 = *(const float4*)(src + 4);
        bf16x8 h;
        h[0] = (__bf16)v0.x; h[1] = (__bf16)v0.y; h[2] = (__bf16)v0.z; h[3] = (__bf16)v0.w;
        h[4] = (__bf16)v1.x; h[5] = (__bf16)v1.y; h[6] = (__bf16)v1.z; h[7] = (__bf16)v1.w;
        *(bf16x8*)&sA[r * E_SZ + ((s8 ^ (r & 15)) << 3)] = h;
    }
#pragma unroll
    for (int k = 0; k < 4; ++k) {
        int i = tid + k * 512;
        int r = i >> 4, s8 = i & 15;
        const float* src = kern + ((size_t)r * P_SZ + p) * E_SZ + s8 * 8;
        float4 v0 = *(const float4*)src;
        float4 v1 = *(const float4*)(src + 4);
        bf16x8 h;
        h[0] = (__bf16)v0.x; h[1] = (__bf16)v0.y; h[2] = (__bf16)v0.z; h[3] = (__bf16)v0.w;
        h[4] = (__bf16)v1.x; h[5] = (__bf16)v1.y; h[6] = (__bf16)v1.z; h[7] = (__bf16)v1.w;
        *(bf16x8*)&sB[r * E_SZ + ((s8 ^ (r & 15)) << 3)] = h;
    }
    __syncthreads();

    const int w = tid >> 6, lane = tid & 63;
    const int l31 = lane & 31, hi = lane >> 5;
    const int mh = w >> 2, ng = w & 3;

    f32x16 acc[2];
#pragma unroll
    for (int mt = 0; mt < 2; ++mt)
#pragma unroll
        for (int j = 0; j < 16; ++j) acc[mt][j] = 0.f;

    const int brow = ng * 32 + l31;
#pragma unroll
    for (int kk = 0; kk < 8; ++kk) {
        const int e8 = kk * 2 + hi;
        bf16x8 bfr = *(const bf16x8*)&sA[brow * E_SZ + ((e8 ^ (brow & 15)) << 3)];
#pragma unroll
        for (int mt = 0; mt < 2; ++mt) {
            int arow = (mh * 2 + mt) * 32 + l31;
            bf16x8 afr = *(const bf16x8*)&sB[arow * E_SZ + ((e8 ^ (arow & 15)) << 3)];
            acc[mt] = __builtin_amdgcn_mfma_f32_32x32x16_bf16(afr, bfr, acc[mt], 0, 0, 0);
        }
    }

    const float* xqp = x + ((size_t)(b0 + brow) * F_SZ + fq) * E_SZ;
    float sv = 0.f;
#pragma unroll
    for (int mt = 0; mt < 2; ++mt) {
        const int dbase = (mh * 2 + mt) * 32 + hi * 4;
#pragma unroll
        for (int q = 0; q < 4; ++q) {
            float4 xq = *(const float4*)(xqp + dbase + q * 8);
            sv += acc[mt][q * 4 + 0] * xq.x + acc[mt][q * 4 + 1] * xq.y
                + acc[mt][q * 4 + 2] * xq.z + acc[mt][q * 4 + 3] * xq.w;
        }
    }
    sv += __shfl_xor(sv, 32);
    if (hi == 0) red[mh][brow] = sv;
    __syncthreads();

    if (tid < 128)
        out[(size_t)(b0 + tid) * P_SZ + p] = red[0][tid] + red[1][tid];
}

extern "C" void kernel_launch(void* const* d_in, const int* in_sizes, int n_in,
                              void* d_out, int out_size, void* d_ws, size_t ws_size,
                              hipStream_t stream) {
    const float* x    = (const float*)d_in[0];   // [2048, 24, 128] f32
    const float* kern = (const float*)d_in[1];   // [128, 276, 128] f32
    float* out = (float*)d_out;                  // [2048, 276] f32

    if (ws_size >= WS_NEED) {
        __bf16* xft = (__bf16*)d_ws;
        __bf16* kb  = xft + XT_ELEMS;
        prepack_all<<<dim3(XPREP_BLKS + KPREP_BLKS), 256, 0, stream>>>(x, kern, xft, kb);
        opn_main<<<dim3(NWG), 512, 0, stream>>>(xft, kb, out);
    } else {
        opn_fallback<<<dim3(P_SZ * 16), 512, 0, stream>>>(x, kern, out);
    }
}

// Round 12
// 56.811 us; speedup vs baseline: 2.0395x; 2.0395x over previous
//
#include <hip/hip_runtime.h>
#include <stdint.h>

#define B_SZ 2048
#define F_SZ 24
#define E_SZ 128
#define P_SZ 276            // F*(F-1)/2
#define NWG  (P_SZ * 8)     // 2208 (8 same-pair blocks; bb round-robins XCDs)

#define XT_ELEMS (B_SZ * F_SZ * E_SZ)   // 6,291,456 (12.6 MB bf16)
#define KB_ELEMS (P_SZ * E_SZ * E_SZ)   // 4,521,984 ( 9.0 MB bf16)
#define WS_NEED  ((size_t)(XT_ELEMS + KB_ELEMS) * 2)   // 21.6 MB

#define XPREP_BLKS (F_SZ * 64)          // 1536  (one per (f, 32-row group))
#define KPREP_BLKS (P_SZ * 4)           // 1104  (one per (p, mt))

typedef __bf16 bf16x8 __attribute__((ext_vector_type(8)));
typedef __bf16 bf16x4 __attribute__((ext_vector_type(4)));
typedef float  f32x16 __attribute__((ext_vector_type(16)));

// ---- prepack ----------------------------------------------------------------
// xft[f][grp<64][slot<512][8]: slot s holds
//   x[grp*32 + (s&31)][f][(s>>6)*16 + ((s>>5)&1)*8 + i]   (bf16)
// Serves MFMA B-fragments (slot = kk*64 + lane) and epilogue Xq reads
// (slot = (2mt+(q>>1))*64 + (q&1)*32 + l31, elem hi*4+i), both coalesced.
// kbf[p][slot<2048][8]: slot = (mt*8+kk)*64 + lane holds the A-fragment
//   K[d = mt*32 + (lane&31)][e = kk*16 + (lane>>5)*8 + i]   (bf16)
// -> each wave's K loads are 32 x 1KB-contiguous dwordx4. No LDS in main.
__global__ __launch_bounds__(256) void prepack_all(
    const float* __restrict__ x, const float* __restrict__ kern,
    __bf16* __restrict__ xft, __bf16* __restrict__ kbf)
{
    const int bid = blockIdx.x;
    const int tid = threadIdx.x;
    __shared__ float sT[32][129];           // +1 pad: conflict-free col reads
    if (bid < XPREP_BLKS) {
        const int f = bid >> 6, grp = bid & 63;
        {
            const int row = tid >> 3, c0 = (tid & 7) * 16;
            const float* src = x + ((size_t)(grp * 32 + row) * F_SZ + f) * E_SZ + c0;
            float4 v0 = ((const float4*)src)[0];
            float4 v1 = ((const float4*)src)[1];
            float4 v2 = ((const float4*)src)[2];
            float4 v3 = ((const float4*)src)[3];
            *(float4*)&sT[row][c0]      = v0;
            *(float4*)&sT[row][c0 + 4]  = v1;
            *(float4*)&sT[row][c0 + 8]  = v2;
            *(float4*)&sT[row][c0 + 12] = v3;
        }
        __syncthreads();
        __bf16* dst = xft + (size_t)(f * 64 + grp) * 4096;
#pragma unroll
        for (int u = 0; u < 2; ++u) {
            const int s = tid * 2 + u;      // slot 0..511
            const int row = s & 31;
            const int e0  = (s >> 6) * 16 + ((s >> 5) & 1) * 8;
            bf16x8 h;
#pragma unroll
            for (int i = 0; i < 8; ++i)
                h[i] = (__bf16)sT[row][e0 + i];
            *(bf16x8*)(dst + s * 8) = h;
        }
    } else {
        const int kb = bid - XPREP_BLKS;
        const int p = kb >> 2, mt = kb & 3; // 32 d-rows x 128 e
        {
            const int row = tid >> 3, c0 = (tid & 7) * 16;
            const float* src = kern + ((size_t)(mt * 32 + row) * P_SZ + p) * E_SZ + c0;
            float4 v0 = ((const float4*)src)[0];
            float4 v1 = ((const float4*)src)[1];
            float4 v2 = ((const float4*)src)[2];
            float4 v3 = ((const float4*)src)[3];
            *(float4*)&sT[row][c0]      = v0;
            *(float4*)&sT[row][c0 + 4]  = v1;
            *(float4*)&sT[row][c0 + 8]  = v2;
            *(float4*)&sT[row][c0 + 12] = v3;
        }
        __syncthreads();
        __bf16* dst = kbf + (size_t)p * 16384 + mt * 4096;
#pragma unroll
        for (int u = 0; u < 2; ++u) {
            const int s = tid * 2 + u;      // slot 0..511 within this mt
            const int lane = s & 63, l31 = lane & 31, hi2 = lane >> 5;
            const int e0 = (s >> 6) * 16 + hi2 * 8;
            bf16x8 h;
#pragma unroll
            for (int i = 0; i < 8; ++i)
                h[i] = (__bf16)sT[l31][e0 + i];
            *(bf16x8*)(dst + s * 8) = h;
        }
    }
}

// ---- main: one block = (pair p, 256-row batch tile). NO LDS, NO barriers,
//      NO DMA: K A-fragments, Xp B-fragments and Xq all load coalesced into
//      registers; the block's 8 waves share the 32KB K slab through L1.
__global__ __launch_bounds__(512) void opn_main(
    const __bf16* __restrict__ xft, const __bf16* __restrict__ kbf,
    float* __restrict__ out)
{
    const int tid = threadIdx.x, w = tid >> 6, lane = tid & 63;
    const int l31 = lane & 31, hi = lane >> 5;
    const int orig = blockIdx.x;
    const int bb = orig & 7;            // batch tile (8 same-pair blocks adjacent)
    const int p  = orig >> 3;           // 0..275

    int fp = 0, rem = p;
    while (rem >= F_SZ - 1 - fp) { rem -= F_SZ - 1 - fp; ++fp; }
    const int fq = fp + 1 + rem;

    const int grp = bb * 8 + w;         // this wave's 32-row batch group

    // Xp MFMA B-fragments: 8 coalesced dwordx4
    bf16x8 xpf[8];
    const __bf16* xpb = xft + (size_t)(fp * 64 + grp) * 4096 + lane * 8;
#pragma unroll
    for (int kk = 0; kk < 8; ++kk)
        xpf[kk] = *(const bf16x8*)(xpb + kk * 512);

    // Xq: 16 coalesced 8B loads; lane (l31,hi), (mt,q) -> d = 32mt+8q+4hi+i
    bf16x4 xqr[4][4];
    const __bf16* xqb = xft + (size_t)(fq * 64 + grp) * 4096 + l31 * 8 + hi * 4;
#pragma unroll
    for (int mt = 0; mt < 4; ++mt)
#pragma unroll
        for (int q = 0; q < 4; ++q)
            xqr[mt][q] = *(const bf16x4*)(xqb + (mt * 2 + (q >> 1)) * 512 + (q & 1) * 256);

    // Per-mt: 8 K A-frag loads (1KB coalesced each) + 8 chained MFMAs +
    // immediate lane-local dot. D layout: col = lane&31 (= b),
    // row(d) = (reg&3) + 8*(reg>>2) + 4*hi + 32*mt.
    const __bf16* kpb = kbf + (size_t)p * 16384 + lane * 8;
    float s0 = 0.f, s1 = 0.f;
#pragma unroll
    for (int mt = 0; mt < 4; ++mt) {
        bf16x8 kf[8];
#pragma unroll
        for (int kk = 0; kk < 8; ++kk)
            kf[kk] = *(const bf16x8*)(kpb + (mt * 8 + kk) * 512);
        f32x16 acc;
#pragma unroll
        for (int q = 0; q < 16; ++q) acc[q] = 0.f;
#pragma unroll
        for (int kk = 0; kk < 8; ++kk)
            acc = __builtin_amdgcn_mfma_f32_32x32x16_bf16(kf[kk], xpf[kk], acc, 0, 0, 0);
#pragma unroll
        for (int q = 0; q < 4; ++q) {
            const bf16x4 xq = xqr[mt][q];
            s0 += acc[q * 4 + 0] * (float)xq[0] + acc[q * 4 + 1] * (float)xq[1];
            s1 += acc[q * 4 + 2] * (float)xq[2] + acc[q * 4 + 3] * (float)xq[3];
        }
    }
    float s = s0 + s1;
    s += __shfl_xor(s, 32);             // combine the two hi row-groups
    if (hi == 0)
        out[(size_t)(grp * 32 + l31) * P_SZ + p] = s;
}

// ---------------- fallback (round-2 kernel, used if ws too small) -----------
__global__ __launch_bounds__(512, 4) void opn_fallback(
    const float* __restrict__ x, const float* __restrict__ kern,
    float* __restrict__ out)
{
    __shared__ short sA[128 * E_SZ];
    __shared__ short sB[E_SZ * E_SZ];
    __shared__ float red[2][128];

    const int tid = threadIdx.x;
    const int orig = blockIdx.x;
    const int nwg2 = P_SZ * 16;
    const int wgid = (orig & 7) * (nwg2 / 8) + (orig >> 3);
    const int p  = wgid >> 4;
    const int bb = wgid & 15;
    const int b0 = bb * 128;

    int fp = 0, rem = p;
    while (rem >= F_SZ - 1 - fp) { rem -= F_SZ - 1 - fp; ++fp; }
    const int fq = fp + 1 + rem;

#pragma unroll
    for (int k = 0; k < 4; ++k) {
        int i = tid + k * 512;
        int r = i >> 4, s8 = i & 15;
        const float* src = x + ((size_t)(b0 + r) * F_SZ + fp) * E_SZ + s8 * 8;
        float4 v0 = *(const float4*)src;
        float4 v1 = *(const float4*)(src + 4);
        bf16x8 h;
        h[0] = (__bf16)v0.x; h[1] = (__bf16)v0.y; h[2] = (__bf16)v0.z; h[3] = (__bf16)v0.w;
        h[4] = (__bf16)v1.x; h[5] = (__bf16)v1.y; h[6] = (__bf16)v1.z; h[7] = (__bf16)v1.w;
        *(bf16x8*)&sA[r * E_SZ + ((s8 ^ (r & 15)) << 3)] = h;
    }
#pragma unroll
    for (int k = 0; k < 4; ++k) {
        int i = tid + k * 512;
        int r = i >> 4, s8 = i & 15;
        const float* src = kern + ((size_t)r * P_SZ + p) * E_SZ + s8 * 8;
        float4 v0 = *(const float4*)src;
        float4 v1 = *(const float4*)(src + 4);
        bf16x8 h;
        h[0] = (__bf16)v0.x; h[1] = (__bf16)v0.y; h[2] = (__bf16)v0.z; h[3] = (__bf16)v0.w;
        h[4] = (__bf16)v1.x; h[5] = (__bf16)v1.y; h[6] = (__bf16)v1.z; h[7] = (__bf16)v1.w;
        *(bf16x8*)&sB[r * E_SZ + ((s8 ^ (r & 15)) << 3)] = h;
    }
    __syncthreads();

    const int w = tid >> 6, lane = tid & 63;
    const int l31 = lane & 31, hi = lane >> 5;
    const int mh = w >> 2, ng = w & 3;

    f32x16 acc[2];
#pragma unroll
    for (int mt = 0; mt < 2; ++mt)
#pragma unroll
        for (int j = 0; j < 16; ++j) acc[mt][j] = 0.f;

    const int brow = ng * 32 + l31;
#pragma unroll
    for (int kk = 0; kk < 8; ++kk) {
        const int e8 = kk * 2 + hi;
        bf16x8 bfr = *(const bf16x8*)&sA[brow * E_SZ + ((e8 ^ (brow & 15)) << 3)];
#pragma unroll
        for (int mt = 0; mt < 2; ++mt) {
            int arow = (mh * 2 + mt) * 32 + l31;
            bf16x8 afr = *(const bf16x8*)&sB[arow * E_SZ + ((e8 ^ (arow & 15)) << 3)];
            acc[mt] = __builtin_amdgcn_mfma_f32_32x32x16_bf16(afr, bfr, acc[mt], 0, 0, 0);
        }
    }

    const float* xqp = x + ((size_t)(b0 + brow) * F_SZ + fq) * E_SZ;
    float sv = 0.f;
#pragma unroll
    for (int mt = 0; mt < 2; ++mt) {
        const int dbase = (mh * 2 + mt) * 32 + hi * 4;
#pragma unroll
        for (int q = 0; q < 4; ++q) {
            float4 xq = *(const float4*)(xqp + dbase + q * 8);
            sv += acc[mt][q * 4 + 0] * xq.x + acc[mt][q * 4 + 1] * xq.y
                + acc[mt][q * 4 + 2] * xq.z + acc[mt][q * 4 + 3] * xq.w;
        }
    }
    sv += __shfl_xor(sv, 32);
    if (hi == 0) red[mh][brow] = sv;
    __syncthreads();

    if (tid < 128)
        out[(size_t)(b0 + tid) * P_SZ + p] = red[0][tid] + red[1][tid];
}

extern "C" void kernel_launch(void* const* d_in, const int* in_sizes, int n_in,
                              void* d_out, int out_size, void* d_ws, size_t ws_size,
                              hipStream_t stream) {
    const float* x    = (const float*)d_in[0];   // [2048, 24, 128] f32
    const float* kern = (const float*)d_in[1];   // [128, 276, 128] f32
    float* out = (float*)d_out;                  // [2048, 276] f32

    if (ws_size >= WS_NEED) {
        __bf16* xft = (__bf16*)d_ws;
        __bf16* kbf = xft + XT_ELEMS;
        prepack_all<<<dim3(XPREP_BLKS + KPREP_BLKS), 256, 0, stream>>>(x, kern, xft, kbf);
        opn_main<<<dim3(NWG), 512, 0, stream>>>(xft, kbf, out);
    } else {
        opn_fallback<<<dim3(P_SZ * 16), 512, 0, stream>>>(x, kern, out);
    }
}

// Round 13
// 50.301 us; speedup vs baseline: 2.3035x; 1.1294x over previous
//
#include <hip/hip_runtime.h>
#include <stdint.h>

#define B_SZ 2048
#define F_SZ 24
#define E_SZ 128
#define P_SZ 276            // F*(F-1)/2
#define NWG  552            // 276 pairs x 2 batch halves = 8 XCDs x 69

#define XT_ELEMS (B_SZ * F_SZ * E_SZ)   // 6,291,456 (12.6 MB bf16)
#define WS_NEED  ((size_t)XT_ELEMS * 2)

#define XPREP_BLKS (F_SZ * 64)          // 1536  (one per (f, 32-row group))

typedef __bf16 bf16x8 __attribute__((ext_vector_type(8)));
typedef __bf16 bf16x4 __attribute__((ext_vector_type(4)));
typedef float  f32x16 __attribute__((ext_vector_type(16)));

// ---- prepack: x only --------------------------------------------------------
// xft[f][grp<64][slot<512][8]: slot s holds
//   x[grp*32 + (s&31)][f][(s>>6)*16 + ((s>>5)&1)*8 + i]   (bf16)
// Serves MFMA B-fragments (slot = kk*64 + lane) and epilogue Xq reads
// (slot = (2mt+(q>>1))*64 + (q&1)*32 + l31, elem hi*4+i), both coalesced.
__global__ __launch_bounds__(256) void prepack_x(
    const float* __restrict__ x, __bf16* __restrict__ xft)
{
    const int bid = blockIdx.x;
    const int tid = threadIdx.x;
    const int f = bid >> 6, grp = bid & 63;
    __shared__ float sT[32][129];           // +1 pad: conflict-free col reads
    {
        const int row = tid >> 3, c0 = (tid & 7) * 16;
        const float* src = x + ((size_t)(grp * 32 + row) * F_SZ + f) * E_SZ + c0;
        float4 v0 = ((const float4*)src)[0];
        float4 v1 = ((const float4*)src)[1];
        float4 v2 = ((const float4*)src)[2];
        float4 v3 = ((const float4*)src)[3];
        *(float4*)&sT[row][c0]      = v0;
        *(float4*)&sT[row][c0 + 4]  = v1;
        *(float4*)&sT[row][c0 + 8]  = v2;
        *(float4*)&sT[row][c0 + 12] = v3;
    }
    __syncthreads();
    __bf16* dst = xft + (size_t)(f * 64 + grp) * 4096;
#pragma unroll
    for (int u = 0; u < 2; ++u) {
        const int s = tid * 2 + u;          // slot 0..511
        const int row = s & 31;
        const int e0  = (s >> 6) * 16 + ((s >> 5) & 1) * 8;
        bf16x8 h;
#pragma unroll
        for (int i = 0; i < 8; ++i)
            h[i] = (__bf16)sT[row][e0 + i];
        *(bf16x8*)(dst + s * 8) = h;
    }
}

// ---- main: one block = (pair p, 1024-row batch half).
//      Phase 1: convert K_p f32 -> swizzled bf16 LDS (once; 64KB coalesced
//      read, 1 barrier). Phase 2: barrier-free loop over 4 batch tiles of
//      256 rows; per wave 256 MFMA total -- 4x the density of prior rounds.
//      XCD (orig&7) -> (pair-quarter, batch-half): K slab 4.4MB f32 +
//      x half 6.3MB per XCD, ~L2-resident.
__global__ __launch_bounds__(512, 4) void opn_main(
    const __bf16* __restrict__ xft, const float* __restrict__ kern,
    float* __restrict__ out)
{
    __shared__ short sK[E_SZ * E_SZ];   // 32 KB swizzled K_p

    const int tid = threadIdx.x, w = tid >> 6, lane = tid & 63;
    const int l31 = lane & 31, hi = lane >> 5;
    const int orig = blockIdx.x;
    const int xcd = orig & 7;
    const int p = ((xcd >> 1) * 69) + (orig >> 3);  // pair 0..275
    const int h = xcd & 1;                          // batch half

    int fp = 0, rem = p;
    while (rem >= F_SZ - 1 - fp) { rem -= F_SZ - 1 - fp; ++fp; }
    const int fq = fp + 1 + rem;

    // ---- phase 1: K_p f32 -> bf16, XOR-swizzled into LDS ----
    // thread: row d = tid>>2, chunk c = tid&3 (32 f32, 128B coalesced)
    {
        const int d = tid >> 2, c = tid & 3;
        const float* kr = kern + ((size_t)d * P_SZ + p) * E_SZ + c * 32;
        float4 v[8];
#pragma unroll
        for (int j = 0; j < 8; ++j) v[j] = ((const float4*)kr)[j];
        const int dsw = d & 15;
#pragma unroll
        for (int j = 0; j < 4; ++j) {
            bf16x8 hh;
            hh[0] = (__bf16)v[2*j].x;   hh[1] = (__bf16)v[2*j].y;
            hh[2] = (__bf16)v[2*j].z;   hh[3] = (__bf16)v[2*j].w;
            hh[4] = (__bf16)v[2*j+1].x; hh[5] = (__bf16)v[2*j+1].y;
            hh[6] = (__bf16)v[2*j+1].z; hh[7] = (__bf16)v[2*j+1].w;
            const int s = c * 4 + j;            // source 16B-slot
            *(bf16x8*)&sK[d * E_SZ + ((s ^ dsw) << 3)] = hh;
        }
    }
    __syncthreads();                    // K ready; no more barriers

    // ---- phase 2: 4 batch tiles of 256 rows ----
#pragma unroll
    for (int t = 0; t < 4; ++t) {
        const int grp = h * 32 + t * 8 + w;     // 32-row batch group

        // Xp MFMA B-fragments: 8 coalesced dwordx4
        bf16x8 xpf[8];
        const __bf16* xpb = xft + (size_t)(fp * 64 + grp) * 4096 + lane * 8;
#pragma unroll
        for (int kk = 0; kk < 8; ++kk)
            xpf[kk] = *(const bf16x8*)(xpb + kk * 512);

        // Xq: 16 coalesced 8B loads; (mt,q) -> d = 32mt+8q+4hi+i
        bf16x4 xqr[4][4];
        const __bf16* xqb = xft + (size_t)(fq * 64 + grp) * 4096 + l31 * 8 + hi * 4;
#pragma unroll
        for (int mt = 0; mt < 4; ++mt)
#pragma unroll
            for (int q = 0; q < 4; ++q)
                xqr[mt][q] = *(const bf16x4*)(xqb + (mt * 2 + (q >> 1)) * 512 + (q & 1) * 256);

        // per-mt: 8 swizzled ds_reads + 8 chained MFMAs + lane-local dot.
        // D layout: col = lane&31 (= b), row(d) = (reg&3)+8*(reg>>2)+4*hi+32mt
        float s0 = 0.f, s1 = 0.f;
#pragma unroll
        for (int mt = 0; mt < 4; ++mt) {
            const int arow = mt * 32 + l31;
            const short* kRow = &sK[arow * E_SZ];
            const int asw = (arow & 15) << 3;
            f32x16 acc;
#pragma unroll
            for (int q = 0; q < 16; ++q) acc[q] = 0.f;
#pragma unroll
            for (int kk = 0; kk < 8; ++kk) {
                bf16x8 afr = *(const bf16x8*)&kRow[((kk * 2 + hi) << 3) ^ asw];
                acc = __builtin_amdgcn_mfma_f32_32x32x16_bf16(afr, xpf[kk], acc, 0, 0, 0);
            }
#pragma unroll
            for (int q = 0; q < 4; ++q) {
                const bf16x4 xq = xqr[mt][q];
                s0 += acc[q * 4 + 0] * (float)xq[0] + acc[q * 4 + 1] * (float)xq[1];
                s1 += acc[q * 4 + 2] * (float)xq[2] + acc[q * 4 + 3] * (float)xq[3];
            }
        }
        float s = s0 + s1;
        s += __shfl_xor(s, 32);         // combine the two hi row-groups
        if (hi == 0)
            out[(size_t)(grp * 32 + l31) * P_SZ + p] = s;
    }
}

// ---------------- fallback (round-2 kernel, used if ws too small) -----------
__global__ __launch_bounds__(512, 4) void opn_fallback(
    const float* __restrict__ x, const float* __restrict__ kern,
    float* __restrict__ out)
{
    __shared__ short sA[128 * E_SZ];
    __shared__ short sB[E_SZ * E_SZ];
    __shared__ float red[2][128];

    const int tid = threadIdx.x;
    const int orig = blockIdx.x;
    const int nwg2 = P_SZ * 16;
    const int wgid = (orig & 7) * (nwg2 / 8) + (orig >> 3);
    const int p  = wgid >> 4;
    const int bb = wgid & 15;
    const int b0 = bb * 128;

    int fp = 0, rem = p;
    while (rem >= F_SZ - 1 - fp) { rem -= F_SZ - 1 - fp; ++fp; }
    const int fq = fp + 1 + rem;

#pragma unroll
    for (int k = 0; k < 4; ++k) {
        int i = tid + k * 512;
        int r = i >> 4, s8 = i & 15;
        const float* src = x + ((size_t)(b0 + r) * F_SZ + fp) * E_SZ + s8 * 8;
        float4 v0 = *(const float4*)src;
        float4 v1 = *(const float4*)(src + 4);
        bf16x8 hh;
        hh[0] = (__bf16)v0.x; hh[1] = (__bf16)v0.y; hh[2] = (__bf16)v0.z; hh[3] = (__bf16)v0.w;
        hh[4] = (__bf16)v1.x; hh[5] = (__bf16)v1.y; hh[6] = (__bf16)v1.z; hh[7] = (__bf16)v1.w;
        *(bf16x8*)&sA[r * E_SZ + ((s8 ^ (r & 15)) << 3)] = hh;
    }
#pragma unroll
    for (int k = 0; k < 4; ++k) {
        int i = tid + k * 512;
        int r = i >> 4, s8 = i & 15;
        const float* src = kern + ((size_t)r * P_SZ + p) * E_SZ + s8 * 8;
        float4 v0 = *(const float4*)src;
        float4 v1 = *(const float4*)(src + 4);
        bf16x8 hh;
        hh[0] = (__bf16)v0.x; hh[1] = (__bf16)v0.y; hh[2] = (__bf16)v0.z; hh[3] = (__bf16)v0.w;
        hh[4] = (__bf16)v1.x; hh[5] = (__bf16)v1.y; hh[6] = (__bf16)v1.z; hh[7] = (__bf16)v1.w;
        *(bf16x8*)&sB[r * E_SZ + ((s8 ^ (r & 15)) << 3)] = hh;
    }
    __syncthreads();

    const int w = tid >> 6, lane = tid & 63;
    const int l31 = lane & 31, hi = lane >> 5;
    const int mh = w >> 2, ng = w & 3;

    f32x16 acc[2];
#pragma unroll
    for (int mt = 0; mt < 2; ++mt)
#pragma unroll
        for (int j = 0; j < 16; ++j) acc[mt][j] = 0.f;

    const int brow = ng * 32 + l31;
#pragma unroll
    for (int kk = 0; kk < 8; ++kk) {
        const int e8 = kk * 2 + hi;
        bf16x8 bfr = *(const bf16x8*)&sA[brow * E_SZ + ((e8 ^ (brow & 15)) << 3)];
#pragma unroll
        for (int mt = 0; mt < 2; ++mt) {
            int arow = (mh * 2 + mt) * 32 + l31;
            bf16x8 afr = *(const bf16x8*)&sB[arow * E_SZ + ((e8 ^ (arow & 15)) << 3)];
            acc[mt] = __builtin_amdgcn_mfma_f32_32x32x16_bf16(afr, bfr, acc[mt], 0, 0, 0);
        }
    }

    const float* xqp = x + ((size_t)(b0 + brow) * F_SZ + fq) * E_SZ;
    float sv = 0.f;
#pragma unroll
    for (int mt = 0; mt < 2; ++mt) {
        const int dbase = (mh * 2 + mt) * 32 + hi * 4;
#pragma unroll
        for (int q = 0; q < 4; ++q) {
            float4 xq = *(const float4*)(xqp + dbase + q * 8);
            sv += acc[mt][q * 4 + 0] * xq.x + acc[mt][q * 4 + 1] * xq.y
                + acc[mt][q * 4 + 2] * xq.z + acc[mt][q * 4 + 3] * xq.w;
        }
    }
    sv += __shfl_xor(sv, 32);
    if (hi == 0) red[mh][brow] = sv;
    __syncthreads();

    if (tid < 128)
        out[(size_t)(b0 + tid) * P_SZ + p] = red[0][tid] + red[1][tid];
}

extern "C" void kernel_launch(void* const* d_in, const int* in_sizes, int n_in,
                              void* d_out, int out_size, void* d_ws, size_t ws_size,
                              hipStream_t stream) {
    const float* x    = (const float*)d_in[0];   // [2048, 24, 128] f32
    const float* kern = (const float*)d_in[1];   // [128, 276, 128] f32
    float* out = (float*)d_out;                  // [2048, 276] f32

    if (ws_size >= WS_NEED) {
        __bf16* xft = (__bf16*)d_ws;
        prepack_x<<<dim3(XPREP_BLKS), 256, 0, stream>>>(x, xft);
        opn_main<<<dim3(NWG), 512, 0, stream>>>(xft, kern, out);
    } else {
        opn_fallback<<<dim3(P_SZ * 16), 512, 0, stream>>>(x, kern, out);
    }
}